// Round 13
// baseline (289.455 us; speedup 1.0000x reference)
//
#include <hip/hip_runtime.h>
#include <hip/hip_bf16.h>

typedef short bf16x8 __attribute__((ext_vector_type(8)));
typedef short bf16x4 __attribute__((ext_vector_type(4)));
typedef float f32x4 __attribute__((ext_vector_type(4)));
typedef unsigned int u32;
typedef unsigned long long u64;

#define GLD_LDS16(gp, lp) \
  __builtin_amdgcn_global_load_lds((const __attribute__((address_space(1))) u32*)(gp), \
                                   (__attribute__((address_space(3))) u32*)(lp), 16, 0, 0)

__device__ __forceinline__ short f2bf(float f) {
  u32 u = __builtin_bit_cast(u32, f);
  u = (u + 0x7fffu + ((u >> 16) & 1u)) >> 16;
  return (short)u;
}

// gfx950 has no cvt_pk_bf16 builtin (m240) -- hardware op via inline asm.
__device__ __forceinline__ u32 pack2_bf16(float a, float b) {
#if __has_builtin(__builtin_amdgcn_cvt_pk_bf16_f32)
  typedef __bf16 bf16v2 __attribute__((ext_vector_type(2)));
  bf16v2 r = __builtin_amdgcn_cvt_pk_bf16_f32(a, b);
  return __builtin_bit_cast(u32, r);
#else
  u32 r;
  asm("v_cvt_pk_bf16_f32 %0, %1, %2" : "=v"(r) : "v"(a), "v"(b));
  return r;
#endif
}

__device__ __forceinline__ float exp2_fast(float x) {
#if __has_builtin(__builtin_amdgcn_exp2f)
  return __builtin_amdgcn_exp2f(x);
#else
  return exp2f(x);
#endif
}

// duplicate two mask bytes of src into bf16 halves: sel [b,b,b',b'] -> 0xFFFF/0 pairs
__device__ __forceinline__ u32 bytemask2(u32 src, u32 sel) {
  u32 r;
  asm("v_perm_b32 %0, %1, %1, %2" : "=v"(r) : "v"(src), "v"(sel));
  return r;
}

// ---------------- fused prep: mask byte-table (8192) + cvt (12288) + rope (128) ----
__global__ __launch_bounds__(256) void prep_all(
    const int* __restrict__ m, unsigned char* __restrict__ maskt,
    const float* __restrict__ hs, const float* __restrict__ wqkv,
    const float* __restrict__ wo, short* __restrict__ xb,
    short* __restrict__ wqkvb, short* __restrict__ wob,
    const float* __restrict__ rpe, float* __restrict__ cosT,
    float* __restrict__ sinT) {
  int b = blockIdx.x;
  if (b < 8192) {
    // t[b][q][k] = m[b][q][k] ? 0xFF : 0  (8 MB, L3-resident)
    int i = b * 1024 + threadIdx.x * 4;
    int4 v = *(const int4*)(m + i);
    uchar4 o;
    o.x = v.x ? 0xFFu : 0u;
    o.y = v.y ? 0xFFu : 0u;
    o.z = v.z ? 0xFFu : 0u;
    o.w = v.w ? 0xFFu : 0u;
    *(uchar4*)(maskt + i) = o;
    return;
  }
  b -= 8192;
  if (b < 12288) {
    const float* in;
    short* out;
    int base;
    if (b < 8192) {
      in = hs; out = xb; base = b * 1024;
    } else if (b < 8192 + 3072) {
      in = wqkv; out = wqkvb; base = (b - 8192) * 1024;
    } else {
      in = wo; out = wob; base = (b - 11264) * 1024;
    }
    int i = base + threadIdx.x * 4;
    float4 v = *(const float4*)(in + i);
    short4 o;
    o.x = f2bf(v.x); o.y = f2bf(v.y); o.z = f2bf(v.z); o.w = f2bf(v.w);
    *(short4*)(out + i) = o;
    return;
  }
  b -= 12288;
  int i = b * 256 + threadIdx.x;  // 32768 = 1024*32
  float v = rpe[i];
  cosT[i] = cosf(v);
  sinT[i] = sinf(v);
}

// ---------------- GEMM 1 v9: 128x128 tile, 3 blocks/CU, CLEAN 2-round tail ----------------
// Round-12 model closure: v7/v8b both ~70us because ceiling = MFMA/LDS-port time
// (~45%, set by 32 FLOP/B intensity of 64x64-per-wave blocking) x 75% tail util
// (768 blocks / 512 slots = 1.5 rounds). v9 keeps the proven v8b schedule + swizzle
// but at 128x128/256thr (2x2 waves), BK=32, 3-buf=48KB -> 3 blocks/CU; grid 1536
// blocks = EXACTLY 2 rounds of 768 slots -> tail ~100%.
// Per K-step: {vmcnt(4); s_barrier; STG(kt+2) [4 GLDs]; 8 ds_reads; 16 MFMA}.
__global__ __launch_bounds__(256, 3) void gemm_qkv(
    const short* __restrict__ Xb, const short* __restrict__ Wb,
    const float* __restrict__ bqkv, const float* __restrict__ cosT,
    const float* __restrict__ sinT, short* __restrict__ qb,
    short* __restrict__ kbuf, short* __restrict__ vbuf) {
  __shared__ short lds[3][8192];  // [buf][A:128x32 | B:128x32] = 16 KB each
  const int tid = threadIdx.x;
  const int wid = tid >> 6, lane = tid & 63;
  const int g = lane >> 4, c = lane & 15;
  const int wm = wid >> 1, wn = wid & 1;
  // XCD swizzle: nwg=1536 (24 x 64), 192 contiguous tiles per XCD
  const int bid = blockIdx.y * 24 + blockIdx.x;
  const int swz = (bid & 7) * 192 + (bid >> 3);
  const int m0 = (swz / 24) * 128, n0 = (swz % 24) * 128;

  f32x4 acc[4][4];
#pragma unroll
  for (int i = 0; i < 4; i++)
#pragma unroll
    for (int j = 0; j < 4; j++) acc[i][j] = (f32x4){0.f, 0.f, 0.f, 0.f};

  // staging: thread t -> row t>>2 (of a 64-row piece), 16B slot t&3 (linear dest);
  // global source chunk = (t&3) ^ f(row), f(row) = (row>>1)&3 = (t>>3)&3 [proven]
  const int trow = tid >> 2;
  const int gch = ((tid & 3) ^ ((tid >> 3) & 3)) * 8;
  const short* Ag = Xb + (long)(m0 + trow) * 1024 + gch;
  const short* Bg = Wb + (long)(n0 + trow) * 1024 + gch;
  const int lo = tid * 8;  // shorts; piece = 256 thr x 16B = 4 KB = 64 rows

  // fragment read: row = wseg*64 + f*16 + c -> f(row) = (c>>1)&3; slot = g ^ f
  const int fA = (wm * 64 + c) * 32;
  const int fB = 4096 + (wn * 64 + c) * 32;
  const int ck0 = (g ^ ((c >> 1) & 3)) * 8;

#define QKV_STG(bs, ko) do { \
    GLD_LDS16(Ag + (ko),              &lds[bs][lo]); \
    GLD_LDS16(Ag + (ko) + 64 * 1024,  &lds[bs][2048 + lo]); \
    GLD_LDS16(Bg + (ko),              &lds[bs][4096 + lo]); \
    GLD_LDS16(Bg + (ko) + 64 * 1024,  &lds[bs][6144 + lo]); \
  } while (0)

  QKV_STG(0, 0);
  QKV_STG(1, 32);

#pragma unroll
  for (int kt = 0; kt < 32; ++kt) {
    // own STG(kt) done (issued 2 iters ago); STG(kt+1)'s 4 stay in flight
    if (kt < 31) {
      asm volatile("s_waitcnt vmcnt(4)" ::: "memory");
    } else {
      asm volatile("s_waitcnt vmcnt(0)" ::: "memory");
    }
    __builtin_amdgcn_s_barrier();
    __builtin_amdgcn_sched_barrier(0);
    if (kt < 30) QKV_STG((kt + 2) % 3, (kt + 2) * 32);
    const short* Bf = &lds[kt % 3][0];
    bf16x8 fa[4], fb[4];
#pragma unroll
    for (int mf = 0; mf < 4; mf++) fa[mf] = *(const bf16x8*)&Bf[fA + mf * 512 + ck0];
#pragma unroll
    for (int nf = 0; nf < 4; nf++) fb[nf] = *(const bf16x8*)&Bf[fB + nf * 512 + ck0];
    __builtin_amdgcn_s_setprio(1);
#pragma unroll
    for (int mf = 0; mf < 4; mf++)
#pragma unroll
      for (int nf = 0; nf < 4; nf++)
        acc[mf][nf] = __builtin_amdgcn_mfma_f32_16x16x32_bf16(fb[nf], fa[mf], acc[mf][nf], 0, 0, 0);
    __builtin_amdgcn_s_setprio(0);
  }
#undef QKV_STG

  // epilogue: lane owns token r (col=c), 4 consecutive channels (rows=g*4+reg)
  for (int jt = 0; jt < 4; jt++) {
    const int chan = n0 + wn * 64 + jt * 16 + g * 4;
    const int three = chan >> 10;
    const int hh = (chan >> 6) & 15;
    const int d = chan & 63;
    const float4 bq = *(const float4*)&bqkv[chan];
    for (int i = 0; i < 4; i++) {
      const int r = m0 + wm * 64 + i * 16 + c;
      const int l = r >> 3, b = r & 7;
      float v0 = acc[i][jt][0] + bq.x;
      float v1 = acc[i][jt][1] + bq.y;
      float v2 = acc[i][jt][2] + bq.z;
      float v3 = acc[i][jt][3] + bq.w;
      const long doff = ((long)(b * 16 + hh) * 1024 + l) * 64 + d;
      if (three == 2) {
        uint2 o = {pack2_bf16(v0, v1), pack2_bf16(v2, v3)};
        *(uint2*)&vbuf[doff] = o;
      } else {
        const float4 cs = *(const float4*)&cosT[l * 32 + (d & 31)];
        const float4 sn = *(const float4*)&sinT[l * 32 + (d & 31)];
        float e0 = v0 * cs.x - v1 * sn.x;
        float o0 = v1 * cs.y + v0 * sn.y;
        float e1 = v2 * cs.z - v3 * sn.z;
        float o1 = v3 * cs.w + v2 * sn.w;
        short* dst;
        if (three == 0) {
          const float S = 0.18033688011f;  // 1/sqrt(D) * log2(e)
          e0 *= S; o0 *= S; e1 *= S; o1 *= S;
          dst = qb;
        } else {
          dst = kbuf;
        }
        uint2 o = {pack2_bf16(e0, o0), pack2_bf16(e1, o1)};
        *(uint2*)&dst[doff] = o;
      }
    }
  }
}

// ---------------- V transpose: (B,H,L,D) -> (B,H,D,L) ----------------
__global__ __launch_bounds__(256) void transpose_v(const short* __restrict__ vbuf,
                                                   short* __restrict__ vTb) {
  __shared__ short T[64 * 72];
  const int bh = blockIdx.y;
  const int l0 = blockIdx.x * 64;
  const int t = threadIdx.x;
  const int row = t >> 3;
  const int cc = (t & 7) * 8;
  const short* src = vbuf + ((long)bh * 1024 + l0) * 64;
  for (int p = 0; p < 2; p++) {
    int lr = row + p * 32;
    *(bf16x8*)&T[lr * 72 + cc] = *(const bf16x8*)&src[(long)lr * 64 + cc];
  }
  __syncthreads();
  short* dst = vTb + (long)bh * 64 * 1024 + l0;
  for (int p = 0; p < 2; p++) {
    int d = row + p * 32;
    bf16x8 v;
    for (int j = 0; j < 8; j++) v[j] = T[(cc + j) * 72 + d];
    *(bf16x8*)&dst[(long)d * 1024 + cc] = v;
  }
}

// ---------------- flash attention v10b (unchanged from round 10, passing) ----------------
__global__ __launch_bounds__(512, 4) void flash_attn(
    const short* __restrict__ qb, const short* __restrict__ kbuf,
    const short* __restrict__ vTb, const unsigned char* __restrict__ maskt,
    short* __restrict__ attno) {
  __shared__ short K0[64 * 64], K1[64 * 64];
  __shared__ short V0[64 * 64], V1[64 * 64];
  const int t = threadIdx.x;
  const int wid = t >> 6, lane = t & 63;
  const int g = lane >> 4, c = lane & 15;
  const int bid = blockIdx.y * 8 + blockIdx.x;
  const int swz = (bid & 7) * 128 + (bid >> 3);
  const int q0 = (swz & 7) * 128;
  const int bh = swz >> 3;
  const int b = bh >> 4;
  const int h = bh & 15;
  const long qoff = (long)bh * 1024 * 64;
  const int qrow = q0 + wid * 16 + c;  // wid 0-7 -> 128 q-rows per block

  const u32 SEL01 = 0x01010000u;  // dst bytes = [b0,b0,b1,b1]
  const u32 SEL23 = 0x03030202u;  // dst bytes = [b2,b2,b3,b3]

  bf16x8 aq0, aq1;
  {
    const short* qp = qb + qoff + (long)qrow * 64;
    aq0 = *(const bf16x8*)(qp + g * 8);
    aq1 = *(const bf16x8*)(qp + 32 + g * 8);
  }

  f32x4 Od[4];
  for (int i = 0; i < 4; i++) Od[i] = (f32x4){0.f, 0.f, 0.f, 0.f};
  f32x4 Ld = (f32x4){0.f, 0.f, 0.f, 0.f};
  float m_run = -1e30f;

  bf16x8 avOnes8;
  {
    union { bf16x8 v; u32 u[4]; } av;
    u32 o1 = (c == 0) ? 0x3F803F80u : 0u;
    av.u[0] = av.u[1] = av.u[2] = av.u[3] = o1;
    avOnes8 = av.v;
  }

  const unsigned char* mrow8 = maskt + ((long)b * 1024 + qrow) * 1024 + g * 8;
  const short* Kg = kbuf + qoff;
  const short* Vg = vTb + qoff;

  const int rr = t >> 3;
  const int sch = (((t & 7) ^ (rr & 7)) & 7) * 8;
  const int kp = (rr & 32) | (((rr & 15) >> 2) << 3) | (((rr >> 4) & 1) << 2) | (rr & 3);
  const int ldsb = (wid * 8) * 64;  // wave-uniform dest base (shorts)

  const int ck0 = g ^ (c & 7);
  const int kOff0 = c * 64 + ck0 * 8;
  const int kOff1 = c * 64 + (ck0 ^ 4) * 8;
  int vOff32[2];
  for (int kg = 0; kg < 2; kg++)
    vOff32[kg] = c * 64 + (((kg * 4 + g) ^ (c & 7)) * 8);

#define STAGE(KD, VD, ktn) do { \
    GLD_LDS16(Kg + (long)((ktn) + kp) * 64 + sch, &KD[ldsb]); \
    GLD_LDS16(Vg + (long)rr * 1024 + (ktn) + sch, &VD[ldsb]); \
  } while (0)

#define TILE(KB, VB, KP, VP, ki) do { \
    __syncthreads(); /* drains prefetch issued a full tile of compute ago */ \
    STAGE(KP, VP, (((ki) + 1) & 15) * 64); \
    const uint2 w0 = *(const uint2*)&mrow8[(ki) * 64]; \
    const uint2 w1 = *(const uint2*)&mrow8[(ki) * 64 + 32]; \
    f32x4 z[4]; \
    __builtin_amdgcn_s_setprio(1); \
    for (int nt = 0; nt < 4; nt++) { \
      bf16x8 bk0 = *(const bf16x8*)&KB[kOff0 + nt * 1024]; \
      bf16x8 bk1 = *(const bf16x8*)&KB[kOff1 + nt * 1024]; \
      f32x4 zz = (f32x4){0.f, 0.f, 0.f, 0.f}; \
      zz = __builtin_amdgcn_mfma_f32_16x16x32_bf16(bk0, aq0, zz, 0, 0, 0); \
      zz = __builtin_amdgcn_mfma_f32_16x16x32_bf16(bk1, aq1, zz, 0, 0, 0); \
      z[nt] = zz; \
    } \
    __builtin_amdgcn_s_setprio(0); \
    float mx = fmaxf(fmaxf(fmaxf(z[0][0], z[0][1]), fmaxf(z[0][2], z[0][3])), \
                     fmaxf(fmaxf(z[1][0], z[1][1]), fmaxf(z[1][2], z[1][3]))); \
    mx = fmaxf(mx, fmaxf(fmaxf(fmaxf(z[2][0], z[2][1]), fmaxf(z[2][2], z[2][3])), \
                         fmaxf(fmaxf(z[3][0], z[3][1]), fmaxf(z[3][2], z[3][3])))); \
    if (__ballot(mx > m_run + 8.f)) { /* rare after warm-up (T13) */ \
      mx = fmaxf(mx, __shfl_xor(mx, 16, 64)); \
      mx = fmaxf(mx, __shfl_xor(mx, 32, 64)); \
      float mnew = fmaxf(m_run, mx); \
      float al = exp2_fast(m_run - mnew); \
      for (int dt = 0; dt < 4; dt++) { \
        Od[dt][0] *= al; Od[dt][1] *= al; Od[dt][2] *= al; Od[dt][3] *= al; \
      } \
      Ld[0] *= al; \
      m_run = mnew; \
    } \
    union { bf16x8 v; u32 u[4]; } puA, puB; \
    { \
      float p0 = exp2_fast(z[0][0] - m_run), p1 = exp2_fast(z[0][1] - m_run); \
      float p2 = exp2_fast(z[0][2] - m_run), p3 = exp2_fast(z[0][3] - m_run); \
      float p4 = exp2_fast(z[1][0] - m_run), p5 = exp2_fast(z[1][1] - m_run); \
      float p6 = exp2_fast(z[1][2] - m_run), p7 = exp2_fast(z[1][3] - m_run); \
      puA.u[0] = pack2_bf16(p0, p1) & bytemask2(w0.x, SEL01); \
      puA.u[1] = pack2_bf16(p2, p3) & bytemask2(w0.x, SEL23); \
      puA.u[2] = pack2_bf16(p4, p5) & bytemask2(w0.y, SEL01); \
      puA.u[3] = pack2_bf16(p6, p7) & bytemask2(w0.y, SEL23); \
    } \
    { \
      float p0 = exp2_fast(z[2][0] - m_run), p1 = exp2_fast(z[2][1] - m_run); \
      float p2 = exp2_fast(z[2][2] - m_run), p3 = exp2_fast(z[2][3] - m_run); \
      float p4 = exp2_fast(z[3][0] - m_run), p5 = exp2_fast(z[3][1] - m_run); \
      float p6 = exp2_fast(z[3][2] - m_run), p7 = exp2_fast(z[3][3] - m_run); \
      puB.u[0] = pack2_bf16(p0, p1) & bytemask2(w1.x, SEL01); \
      puB.u[1] = pack2_bf16(p2, p3) & bytemask2(w1.x, SEL23); \
      puB.u[2] = pack2_bf16(p4, p5) & bytemask2(w1.y, SEL01); \
      puB.u[3] = pack2_bf16(p6, p7) & bytemask2(w1.y, SEL23); \
    } \
    __builtin_amdgcn_s_setprio(1); \
    Ld = __builtin_amdgcn_mfma_f32_16x16x32_bf16(avOnes8, puA.v, Ld, 0, 0, 0); \
    for (int dt = 0; dt < 4; dt++) { \
      bf16x8 av = *(const bf16x8*)&VB[vOff32[0] + dt * 1024]; \
      Od[dt] = __builtin_amdgcn_mfma_f32_16x16x32_bf16(av, puA.v, Od[dt], 0, 0, 0); \
    } \
    Ld = __builtin_amdgcn_mfma_f32_16x16x32_bf16(avOnes8, puB.v, Ld, 0, 0, 0); \
    for (int dt = 0; dt < 4; dt++) { \
      bf16x8 av = *(const bf16x8*)&VB[vOff32[1] + dt * 1024]; \
      Od[dt] = __builtin_amdgcn_mfma_f32_16x16x32_bf16(av, puB.v, Od[dt], 0, 0, 0); \
    } \
    __builtin_amdgcn_s_setprio(0); \
  } while (0)

  STAGE(K0, V0, 0);
  for (int ki = 0; ki < 16; ki += 2) {
    TILE(K0, V0, K1, V1, ki);
    TILE(K1, V1, K0, V0, ki + 1);
  }
#undef TILE
#undef STAGE

  float lsum = __shfl(Ld[0], c, 64);
  float inv = 1.f / lsum;
  long rbase = ((long)qrow * 8 + b) * 1024 + h * 64 + g * 4;
  for (int dt = 0; dt < 4; dt++) {
    union { bf16x4 v; u32 u[2]; } o;
    o.u[0] = pack2_bf16(Od[dt][0] * inv, Od[dt][1] * inv);
    o.u[1] = pack2_bf16(Od[dt][2] * inv, Od[dt][3] * inv);
    *(bf16x4*)&attno[rbase + dt * 16] = o.v;
  }
}

// ---------------- GEMM 2 v4 (proven in 286/304 builds) ----------------
__global__ __launch_bounds__(256, 3) void gemm_out(
    const short* __restrict__ Ab, const short* __restrict__ Wob,
    const float* __restrict__ bo, float* __restrict__ out) {
  __shared__ short Ash[3][4096];
  __shared__ short Bsh[3][4096];
  const int tid = threadIdx.x;
  const int wid = tid >> 6, lane = tid & 63;
  const int g = lane >> 4, c = lane & 15;
  const int wm = wid >> 1, wn = wid & 1;
  const int bid = blockIdx.y * 8 + blockIdx.x;
  const int swz = (bid & 7) * 64 + (bid >> 3);
  const int m0 = (swz >> 3) * 128, n0 = (swz & 7) * 128;

  f32x4 acc[4][4];
#pragma unroll
  for (int i = 0; i < 4; i++)
#pragma unroll
    for (int j = 0; j < 4; j++) acc[i][j] = (f32x4){0.f, 0.f, 0.f, 0.f};

  const int srow = lane >> 2;
  const int scol = ((lane & 3) ^ ((lane >> 3) & 3)) * 8;
  const short* AgL = Ab + (long)(m0 + wid * 32 + srow) * 1024 + scol;
  const short* BgL = Wob + (long)(n0 + wid * 32 + srow) * 1024 + scol;
  const int dst0 = (wid * 32) * 32;
  const int dst1 = (wid * 32 + 16) * 32;
  const int ck = g ^ ((c >> 1) & 3);

#define OUT_STG(bs, ko) do { \
    GLD_LDS16(AgL + (ko), &Ash[bs][dst0]); \
    GLD_LDS16(AgL + (ko) + 16 * 1024, &Ash[bs][dst1]); \
    GLD_LDS16(BgL + (ko), &Bsh[bs][dst0]); \
    GLD_LDS16(BgL + (ko) + 16 * 1024, &Bsh[bs][dst1]); \
  } while (0)

  OUT_STG(0, 0);
  OUT_STG(1, 32);
  asm volatile("s_waitcnt vmcnt(4)" ::: "memory");
  __builtin_amdgcn_s_barrier();

  bf16x8 af[2][4], bfr[2][4];
#pragma unroll
  for (int i = 0; i < 4; i++)
    af[0][i] = *(const bf16x8*)&Ash[0][(wm * 64 + i * 16 + c) * 32 + ck * 8];
#pragma unroll
  for (int j = 0; j < 4; j++)
    bfr[0][j] = *(const bf16x8*)&Bsh[0][(wn * 64 + j * 16 + c) * 32 + ck * 8];

#pragma unroll
  for (int kt = 0; kt < 32; ++kt) {
    const int cur = kt & 1, nxt = cur ^ 1;
    __builtin_amdgcn_s_setprio(1);
#pragma unroll
    for (int i = 0; i < 2; i++)
#pragma unroll
      for (int j = 0; j < 4; j++)
        acc[i][j] = __builtin_amdgcn_mfma_f32_16x16x32_bf16(af[cur][i], bfr[cur][j], acc[i][j], 0, 0, 0);
    __builtin_amdgcn_s_setprio(0);
    __builtin_amdgcn_sched_barrier(0);
    if (kt < 31) {
      asm volatile("s_waitcnt vmcnt(0)" ::: "memory");
      __builtin_amdgcn_s_barrier();
      if (kt < 30) OUT_STG((kt + 2) % 3, (kt + 2) * 32);
      const int bn = (kt + 1) % 3;
#pragma unroll
      for (int i = 0; i < 4; i++)
        af[nxt][i] = *(const bf16x8*)&Ash[bn][(wm * 64 + i * 16 + c) * 32 + ck * 8];
#pragma unroll
      for (int j = 0; j < 4; j++)
        bfr[nxt][j] = *(const bf16x8*)&Bsh[bn][(wn * 64 + j * 16 + c) * 32 + ck * 8];
      __builtin_amdgcn_sched_barrier(0);
    }
    __builtin_amdgcn_s_setprio(1);
#pragma unroll
    for (int i = 2; i < 4; i++)
#pragma unroll
      for (int j = 0; j < 4; j++)
        acc[i][j] = __builtin_amdgcn_mfma_f32_16x16x32_bf16(af[cur][i], bfr[cur][j], acc[i][j], 0, 0, 0);
    __builtin_amdgcn_s_setprio(0);
  }
#undef OUT_STG

  for (int jt = 0; jt < 4; jt++) {
    const int j = n0 + wn * 64 + jt * 16 + c;
    const float bias = bo[j];
    for (int i = 0; i < 4; i++) {
      const int rbase = m0 + wm * 64 + i * 16 + g * 4;
      for (int reg = 0; reg < 4; reg++)
        out[(long)(rbase + reg) * 1024 + j] = acc[i][jt][reg] + bias;
    }
  }
}

// ---------------- launcher ----------------
extern "C" void kernel_launch(void* const* d_in, const int* in_sizes, int n_in,
                              void* d_out, int out_size, void* d_ws, size_t ws_size,
                              hipStream_t stream) {
  const float* hs = (const float*)d_in[0];
  const float* rpe = (const float*)d_in[1];
  const int* amask = (const int*)d_in[2];
  const float* Wqkv = (const float*)d_in[3];
  const float* bqkv = (const float*)d_in[4];
  const float* Wo = (const float*)d_in[5];
  const float* bo = (const float*)d_in[6];
  float* out = (float*)d_out;

  char* ws = (char*)d_ws;
  auto alloc = [&](size_t bytes) {
    char* p = ws;
    ws += (bytes + 255) & ~(size_t)255;
    return p;
  };
  short* Xb = (short*)alloc(8192LL * 1024 * 2);
  short* Wqkvb = (short*)alloc(3072LL * 1024 * 2);
  short* Wob = (short*)alloc(1024LL * 1024 * 2);
  float* cosT = (float*)alloc(1024 * 32 * 4);
  float* sinT = (float*)alloc(1024 * 32 * 4);
  unsigned char* maskt = (unsigned char*)alloc(8LL * 1024 * 1024);  // byte mask table
  short* qb = (short*)alloc(128LL * 1024 * 64 * 2);
  short* kbuf = (short*)alloc(128LL * 1024 * 64 * 2);
  short* vbuf = (short*)alloc(128LL * 1024 * 64 * 2);
  short* vTb = (short*)alloc(128LL * 1024 * 64 * 2);
  short* attno = (short*)alloc(8192LL * 1024 * 2);

  prep_all<<<20608, 256, 0, stream>>>(amask, maskt, hs, Wqkv, Wo, Xb, Wqkvb, Wob,
                                      rpe, cosT, sinT);
  gemm_qkv<<<dim3(24, 64), 256, 0, stream>>>(Xb, Wqkvb, bqkv, cosT, sinT, qb, kbuf, vbuf);
  transpose_v<<<dim3(16, 128), 256, 0, stream>>>(vbuf, vTb);
  flash_attn<<<dim3(8, 128), 512, 0, stream>>>(qb, kbuf, vTb, maskt, attno);
  gemm_out<<<dim3(8, 64), 256, 0, stream>>>(attno, Wob, bo, out);
}

// Round 14
// 285.298 us; speedup vs baseline: 1.0146x; 1.0146x over previous
//
#include <hip/hip_runtime.h>
#include <hip/hip_bf16.h>

typedef short bf16x8 __attribute__((ext_vector_type(8)));
typedef short bf16x4 __attribute__((ext_vector_type(4)));
typedef float f32x4 __attribute__((ext_vector_type(4)));
typedef unsigned int u32;
typedef unsigned long long u64;

#define GLD_LDS16(gp, lp) \
  __builtin_amdgcn_global_load_lds((const __attribute__((address_space(1))) u32*)(gp), \
                                   (__attribute__((address_space(3))) u32*)(lp), 16, 0, 0)

__device__ __forceinline__ short f2bf(float f) {
  u32 u = __builtin_bit_cast(u32, f);
  u = (u + 0x7fffu + ((u >> 16) & 1u)) >> 16;
  return (short)u;
}

// gfx950 has no cvt_pk_bf16 builtin (m240) -- hardware op via inline asm.
__device__ __forceinline__ u32 pack2_bf16(float a, float b) {
#if __has_builtin(__builtin_amdgcn_cvt_pk_bf16_f32)
  typedef __bf16 bf16v2 __attribute__((ext_vector_type(2)));
  bf16v2 r = __builtin_amdgcn_cvt_pk_bf16_f32(a, b);
  return __builtin_bit_cast(u32, r);
#else
  u32 r;
  asm("v_cvt_pk_bf16_f32 %0, %1, %2" : "=v"(r) : "v"(a), "v"(b));
  return r;
#endif
}

__device__ __forceinline__ float exp2_fast(float x) {
#if __has_builtin(__builtin_amdgcn_exp2f)
  return __builtin_amdgcn_exp2f(x);
#else
  return exp2f(x);
#endif
}

// duplicate two mask bytes of src into bf16 halves: sel [b,b,b',b'] -> 0xFFFF/0 pairs
__device__ __forceinline__ u32 bytemask2(u32 src, u32 sel) {
  u32 r;
  asm("v_perm_b32 %0, %1, %1, %2" : "=v"(r) : "v"(src), "v"(sel));
  return r;
}

// ---------------- fused prep: mask byte-table (8192) + cvt (12288) + rope (128) ----
__global__ __launch_bounds__(256) void prep_all(
    const int* __restrict__ m, unsigned char* __restrict__ maskt,
    const float* __restrict__ hs, const float* __restrict__ wqkv,
    const float* __restrict__ wo, short* __restrict__ xb,
    short* __restrict__ wqkvb, short* __restrict__ wob,
    const float* __restrict__ rpe, float* __restrict__ cosT,
    float* __restrict__ sinT) {
  int b = blockIdx.x;
  if (b < 8192) {
    // t[b][q][k] = m[b][q][k] ? 0xFF : 0  (8 MB, L3-resident)
    int i = b * 1024 + threadIdx.x * 4;
    int4 v = *(const int4*)(m + i);
    uchar4 o;
    o.x = v.x ? 0xFFu : 0u;
    o.y = v.y ? 0xFFu : 0u;
    o.z = v.z ? 0xFFu : 0u;
    o.w = v.w ? 0xFFu : 0u;
    *(uchar4*)(maskt + i) = o;
    return;
  }
  b -= 8192;
  if (b < 12288) {
    const float* in;
    short* out;
    int base;
    if (b < 8192) {
      in = hs; out = xb; base = b * 1024;
    } else if (b < 8192 + 3072) {
      in = wqkv; out = wqkvb; base = (b - 8192) * 1024;
    } else {
      in = wo; out = wob; base = (b - 11264) * 1024;
    }
    int i = base + threadIdx.x * 4;
    float4 v = *(const float4*)(in + i);
    short4 o;
    o.x = f2bf(v.x); o.y = f2bf(v.y); o.z = f2bf(v.z); o.w = f2bf(v.w);
    *(short4*)(out + i) = o;
    return;
  }
  b -= 12288;
  int i = b * 256 + threadIdx.x;  // 32768 = 1024*32
  float v = rpe[i];
  cosT[i] = cosf(v);
  sinT[i] = sinf(v);
}

// ---------------- GEMM 1 v10: per-wave 64x128 (2x LDS intensity) ----------------
// r13 lesson: 128x128 tile doubles A re-reads (FETCH 150MB) -> revert to 128x256.
// r12 model: v8b's 70us = LDS-port ceiling 45% (512 B LDS-read per MFMA at 64x64
// per wave) x 67% sync eff. v10 keeps v8b's EXACT schedule/swizzle/tile but uses
// 4 waves (2Mx2N), per-wave 64x128: 12 frag-reads feed 32 MFMAs = 375 B/MFMA ->
// ceiling ~55%. acc[4][8]=128 VGPR; fb read in 2 batches of 4 to cap live regs
// (~190 total, fits 2 waves/SIMD). 3x24KB LDS -> 2 blocks/CU = 8 waves.
// Per K-step: {vmcnt(6); s_barrier; STG(kt+2) [6 GLDs]; 12 ds_reads; 32 MFMA}.
__global__ __launch_bounds__(256, 2) void gemm_qkv(
    const short* __restrict__ Xb, const short* __restrict__ Wb,
    const float* __restrict__ bqkv, const float* __restrict__ cosT,
    const float* __restrict__ sinT, short* __restrict__ qb,
    short* __restrict__ kbuf, short* __restrict__ vbuf) {
  __shared__ short lds[3][12288];  // [buf][A:128x32 (4096) | B:256x32 (8192)]
  const int tid = threadIdx.x;
  const int wid = tid >> 6, lane = tid & 63;
  const int g = lane >> 4, c = lane & 15;
  const int wm = wid >> 1, wn = wid & 1;  // 2M x 2N, per-wave 64 x 128
  const int bid = blockIdx.y * 12 + blockIdx.x;
  const int swz = (bid & 7) * 96 + (bid >> 3);
  const int m0 = (swz / 12) * 128, n0 = (swz % 12) * 256;

  f32x4 acc[4][8];
#pragma unroll
  for (int i = 0; i < 4; i++)
#pragma unroll
    for (int j = 0; j < 8; j++) acc[i][j] = (f32x4){0.f, 0.f, 0.f, 0.f};

  // staging: 256 thr x 6 pieces of 4KB (64 rows x 32 cols). thread t -> row t>>2,
  // 16B slot t&3 (linear dest); source chunk = (t&3) ^ f(row), f=(row>>1)&3 [proven]
  const int trow = tid >> 2;
  const int gch = ((tid & 3) ^ ((tid >> 3) & 3)) * 8;
  const short* Ag = Xb + (long)(m0 + trow) * 1024 + gch;
  const short* Bg = Wb + (long)(n0 + trow) * 1024 + gch;
  const int lo = tid * 8;  // shorts within a 2048-short piece

  // fragment read: f(row) = (c>>1)&3 (row bits 1-2 come from c); slot = g ^ f
  const int fA = (wm * 64 + c) * 32;
  const int fB = 4096 + (wn * 128 + c) * 32;  // nf stride 512; nf>=4 -> +2048
  const int ck0 = (g ^ ((c >> 1) & 3)) * 8;

#define QKV_STG(bs, ko) do { \
    GLD_LDS16(Ag + (ko),               &lds[bs][lo]); \
    GLD_LDS16(Ag + (ko) + 64 * 1024,   &lds[bs][2048 + lo]); \
    GLD_LDS16(Bg + (ko),               &lds[bs][4096 + lo]); \
    GLD_LDS16(Bg + (ko) + 64 * 1024,   &lds[bs][6144 + lo]); \
    GLD_LDS16(Bg + (ko) + 128 * 1024,  &lds[bs][8192 + lo]); \
    GLD_LDS16(Bg + (ko) + 192 * 1024,  &lds[bs][10240 + lo]); \
  } while (0)

  QKV_STG(0, 0);
  QKV_STG(1, 32);

#pragma unroll
  for (int kt = 0; kt < 32; ++kt) {
    // own STG(kt) done (issued 2 iters ago); STG(kt+1)'s 6 stay in flight
    if (kt < 31) {
      asm volatile("s_waitcnt vmcnt(6)" ::: "memory");
    } else {
      asm volatile("s_waitcnt vmcnt(0)" ::: "memory");
    }
    __builtin_amdgcn_s_barrier();
    __builtin_amdgcn_sched_barrier(0);
    if (kt < 30) QKV_STG((kt + 2) % 3, (kt + 2) * 32);
    const short* Bf = &lds[kt % 3][0];
    bf16x8 fa[4], fb[4];
#pragma unroll
    for (int mf = 0; mf < 4; mf++) fa[mf] = *(const bf16x8*)&Bf[fA + mf * 512 + ck0];
    // N-half 0
#pragma unroll
    for (int nf = 0; nf < 4; nf++) fb[nf] = *(const bf16x8*)&Bf[fB + nf * 512 + ck0];
    __builtin_amdgcn_s_setprio(1);
#pragma unroll
    for (int mf = 0; mf < 4; mf++)
#pragma unroll
      for (int nf = 0; nf < 4; nf++)
        acc[mf][nf] = __builtin_amdgcn_mfma_f32_16x16x32_bf16(fb[nf], fa[mf], acc[mf][nf], 0, 0, 0);
    __builtin_amdgcn_s_setprio(0);
    // N-half 1 (rows wn*128+64..): reuse fb regs to cap live VGPRs
#pragma unroll
    for (int nf = 0; nf < 4; nf++) fb[nf] = *(const bf16x8*)&Bf[fB + 2048 + nf * 512 + ck0];
    __builtin_amdgcn_s_setprio(1);
#pragma unroll
    for (int mf = 0; mf < 4; mf++)
#pragma unroll
      for (int nf = 0; nf < 4; nf++)
        acc[mf][nf + 4] = __builtin_amdgcn_mfma_f32_16x16x32_bf16(fb[nf], fa[mf], acc[mf][nf + 4], 0, 0, 0);
    __builtin_amdgcn_s_setprio(0);
  }
#undef QKV_STG

  // epilogue: lane owns token r (col=c), 4 consecutive channels (rows=g*4+reg)
  for (int jt = 0; jt < 8; jt++) {
    const int chan = n0 + wn * 128 + jt * 16 + g * 4;
    const int three = chan >> 10;
    const int hh = (chan >> 6) & 15;
    const int d = chan & 63;
    const float4 bq = *(const float4*)&bqkv[chan];
    for (int i = 0; i < 4; i++) {
      const int r = m0 + wm * 64 + i * 16 + c;
      const int l = r >> 3, b = r & 7;
      float v0 = acc[i][jt][0] + bq.x;
      float v1 = acc[i][jt][1] + bq.y;
      float v2 = acc[i][jt][2] + bq.z;
      float v3 = acc[i][jt][3] + bq.w;
      const long doff = ((long)(b * 16 + hh) * 1024 + l) * 64 + d;
      if (three == 2) {
        uint2 o = {pack2_bf16(v0, v1), pack2_bf16(v2, v3)};
        *(uint2*)&vbuf[doff] = o;
      } else {
        const float4 cs = *(const float4*)&cosT[l * 32 + (d & 31)];
        const float4 sn = *(const float4*)&sinT[l * 32 + (d & 31)];
        float e0 = v0 * cs.x - v1 * sn.x;
        float o0 = v1 * cs.y + v0 * sn.y;
        float e1 = v2 * cs.z - v3 * sn.z;
        float o1 = v3 * cs.w + v2 * sn.w;
        short* dst;
        if (three == 0) {
          const float S = 0.18033688011f;  // 1/sqrt(D) * log2(e)
          e0 *= S; o0 *= S; e1 *= S; o1 *= S;
          dst = qb;
        } else {
          dst = kbuf;
        }
        uint2 o = {pack2_bf16(e0, o0), pack2_bf16(e1, o1)};
        *(uint2*)&dst[doff] = o;
      }
    }
  }
}

// ---------------- V transpose: (B,H,L,D) -> (B,H,D,L) ----------------
__global__ __launch_bounds__(256) void transpose_v(const short* __restrict__ vbuf,
                                                   short* __restrict__ vTb) {
  __shared__ short T[64 * 72];
  const int bh = blockIdx.y;
  const int l0 = blockIdx.x * 64;
  const int t = threadIdx.x;
  const int row = t >> 3;
  const int cc = (t & 7) * 8;
  const short* src = vbuf + ((long)bh * 1024 + l0) * 64;
  for (int p = 0; p < 2; p++) {
    int lr = row + p * 32;
    *(bf16x8*)&T[lr * 72 + cc] = *(const bf16x8*)&src[(long)lr * 64 + cc];
  }
  __syncthreads();
  short* dst = vTb + (long)bh * 64 * 1024 + l0;
  for (int p = 0; p < 2; p++) {
    int d = row + p * 32;
    bf16x8 v;
    for (int j = 0; j < 8; j++) v[j] = T[(cc + j) * 72 + d];
    *(bf16x8*)&dst[(long)d * 1024 + cc] = v;
  }
}

// ---------------- flash attention v10b (unchanged, passing) ----------------
__global__ __launch_bounds__(512, 4) void flash_attn(
    const short* __restrict__ qb, const short* __restrict__ kbuf,
    const short* __restrict__ vTb, const unsigned char* __restrict__ maskt,
    short* __restrict__ attno) {
  __shared__ short K0[64 * 64], K1[64 * 64];
  __shared__ short V0[64 * 64], V1[64 * 64];
  const int t = threadIdx.x;
  const int wid = t >> 6, lane = t & 63;
  const int g = lane >> 4, c = lane & 15;
  const int bid = blockIdx.y * 8 + blockIdx.x;
  const int swz = (bid & 7) * 128 + (bid >> 3);
  const int q0 = (swz & 7) * 128;
  const int bh = swz >> 3;
  const int b = bh >> 4;
  const int h = bh & 15;
  const long qoff = (long)bh * 1024 * 64;
  const int qrow = q0 + wid * 16 + c;  // wid 0-7 -> 128 q-rows per block

  const u32 SEL01 = 0x01010000u;  // dst bytes = [b0,b0,b1,b1]
  const u32 SEL23 = 0x03030202u;  // dst bytes = [b2,b2,b3,b3]

  bf16x8 aq0, aq1;
  {
    const short* qp = qb + qoff + (long)qrow * 64;
    aq0 = *(const bf16x8*)(qp + g * 8);
    aq1 = *(const bf16x8*)(qp + 32 + g * 8);
  }

  f32x4 Od[4];
  for (int i = 0; i < 4; i++) Od[i] = (f32x4){0.f, 0.f, 0.f, 0.f};
  f32x4 Ld = (f32x4){0.f, 0.f, 0.f, 0.f};
  float m_run = -1e30f;

  bf16x8 avOnes8;
  {
    union { bf16x8 v; u32 u[4]; } av;
    u32 o1 = (c == 0) ? 0x3F803F80u : 0u;
    av.u[0] = av.u[1] = av.u[2] = av.u[3] = o1;
    avOnes8 = av.v;
  }

  const unsigned char* mrow8 = maskt + ((long)b * 1024 + qrow) * 1024 + g * 8;
  const short* Kg = kbuf + qoff;
  const short* Vg = vTb + qoff;

  const int rr = t >> 3;
  const int sch = (((t & 7) ^ (rr & 7)) & 7) * 8;
  const int kp = (rr & 32) | (((rr & 15) >> 2) << 3) | (((rr >> 4) & 1) << 2) | (rr & 3);
  const int ldsb = (wid * 8) * 64;  // wave-uniform dest base (shorts)

  const int ck0 = g ^ (c & 7);
  const int kOff0 = c * 64 + ck0 * 8;
  const int kOff1 = c * 64 + (ck0 ^ 4) * 8;
  int vOff32[2];
  for (int kg = 0; kg < 2; kg++)
    vOff32[kg] = c * 64 + (((kg * 4 + g) ^ (c & 7)) * 8);

#define STAGE(KD, VD, ktn) do { \
    GLD_LDS16(Kg + (long)((ktn) + kp) * 64 + sch, &KD[ldsb]); \
    GLD_LDS16(Vg + (long)rr * 1024 + (ktn) + sch, &VD[ldsb]); \
  } while (0)

#define TILE(KB, VB, KP, VP, ki) do { \
    __syncthreads(); /* drains prefetch issued a full tile of compute ago */ \
    STAGE(KP, VP, (((ki) + 1) & 15) * 64); \
    const uint2 w0 = *(const uint2*)&mrow8[(ki) * 64]; \
    const uint2 w1 = *(const uint2*)&mrow8[(ki) * 64 + 32]; \
    f32x4 z[4]; \
    __builtin_amdgcn_s_setprio(1); \
    for (int nt = 0; nt < 4; nt++) { \
      bf16x8 bk0 = *(const bf16x8*)&KB[kOff0 + nt * 1024]; \
      bf16x8 bk1 = *(const bf16x8*)&KB[kOff1 + nt * 1024]; \
      f32x4 zz = (f32x4){0.f, 0.f, 0.f, 0.f}; \
      zz = __builtin_amdgcn_mfma_f32_16x16x32_bf16(bk0, aq0, zz, 0, 0, 0); \
      zz = __builtin_amdgcn_mfma_f32_16x16x32_bf16(bk1, aq1, zz, 0, 0, 0); \
      z[nt] = zz; \
    } \
    __builtin_amdgcn_s_setprio(0); \
    float mx = fmaxf(fmaxf(fmaxf(z[0][0], z[0][1]), fmaxf(z[0][2], z[0][3])), \
                     fmaxf(fmaxf(z[1][0], z[1][1]), fmaxf(z[1][2], z[1][3]))); \
    mx = fmaxf(mx, fmaxf(fmaxf(fmaxf(z[2][0], z[2][1]), fmaxf(z[2][2], z[2][3])), \
                         fmaxf(fmaxf(z[3][0], z[3][1]), fmaxf(z[3][2], z[3][3])))); \
    if (__ballot(mx > m_run + 8.f)) { /* rare after warm-up (T13) */ \
      mx = fmaxf(mx, __shfl_xor(mx, 16, 64)); \
      mx = fmaxf(mx, __shfl_xor(mx, 32, 64)); \
      float mnew = fmaxf(m_run, mx); \
      float al = exp2_fast(m_run - mnew); \
      for (int dt = 0; dt < 4; dt++) { \
        Od[dt][0] *= al; Od[dt][1] *= al; Od[dt][2] *= al; Od[dt][3] *= al; \
      } \
      Ld[0] *= al; \
      m_run = mnew; \
    } \
    union { bf16x8 v; u32 u[4]; } puA, puB; \
    { \
      float p0 = exp2_fast(z[0][0] - m_run), p1 = exp2_fast(z[0][1] - m_run); \
      float p2 = exp2_fast(z[0][2] - m_run), p3 = exp2_fast(z[0][3] - m_run); \
      float p4 = exp2_fast(z[1][0] - m_run), p5 = exp2_fast(z[1][1] - m_run); \
      float p6 = exp2_fast(z[1][2] - m_run), p7 = exp2_fast(z[1][3] - m_run); \
      puA.u[0] = pack2_bf16(p0, p1) & bytemask2(w0.x, SEL01); \
      puA.u[1] = pack2_bf16(p2, p3) & bytemask2(w0.x, SEL23); \
      puA.u[2] = pack2_bf16(p4, p5) & bytemask2(w0.y, SEL01); \
      puA.u[3] = pack2_bf16(p6, p7) & bytemask2(w0.y, SEL23); \
    } \
    { \
      float p0 = exp2_fast(z[2][0] - m_run), p1 = exp2_fast(z[2][1] - m_run); \
      float p2 = exp2_fast(z[2][2] - m_run), p3 = exp2_fast(z[2][3] - m_run); \
      float p4 = exp2_fast(z[3][0] - m_run), p5 = exp2_fast(z[3][1] - m_run); \
      float p6 = exp2_fast(z[3][2] - m_run), p7 = exp2_fast(z[3][3] - m_run); \
      puB.u[0] = pack2_bf16(p0, p1) & bytemask2(w1.x, SEL01); \
      puB.u[1] = pack2_bf16(p2, p3) & bytemask2(w1.x, SEL23); \
      puB.u[2] = pack2_bf16(p4, p5) & bytemask2(w1.y, SEL01); \
      puB.u[3] = pack2_bf16(p6, p7) & bytemask2(w1.y, SEL23); \
    } \
    __builtin_amdgcn_s_setprio(1); \
    Ld = __builtin_amdgcn_mfma_f32_16x16x32_bf16(avOnes8, puA.v, Ld, 0, 0, 0); \
    for (int dt = 0; dt < 4; dt++) { \
      bf16x8 av = *(const bf16x8*)&VB[vOff32[0] + dt * 1024]; \
      Od[dt] = __builtin_amdgcn_mfma_f32_16x16x32_bf16(av, puA.v, Od[dt], 0, 0, 0); \
    } \
    Ld = __builtin_amdgcn_mfma_f32_16x16x32_bf16(avOnes8, puB.v, Ld, 0, 0, 0); \
    for (int dt = 0; dt < 4; dt++) { \
      bf16x8 av = *(const bf16x8*)&VB[vOff32[1] + dt * 1024]; \
      Od[dt] = __builtin_amdgcn_mfma_f32_16x16x32_bf16(av, puB.v, Od[dt], 0, 0, 0); \
    } \
    __builtin_amdgcn_s_setprio(0); \
  } while (0)

  STAGE(K0, V0, 0);
  for (int ki = 0; ki < 16; ki += 2) {
    TILE(K0, V0, K1, V1, ki);
    TILE(K1, V1, K0, V0, ki + 1);
  }
#undef TILE
#undef STAGE

  float lsum = __shfl(Ld[0], c, 64);
  float inv = 1.f / lsum;
  long rbase = ((long)qrow * 8 + b) * 1024 + h * 64 + g * 4;
  for (int dt = 0; dt < 4; dt++) {
    union { bf16x4 v; u32 u[2]; } o;
    o.u[0] = pack2_bf16(Od[dt][0] * inv, Od[dt][1] * inv);
    o.u[1] = pack2_bf16(Od[dt][2] * inv, Od[dt][3] * inv);
    *(bf16x4*)&attno[rbase + dt * 16] = o.v;
  }
}

// ---------------- GEMM 2 v4 (proven in 280/282/286 builds) ----------------
__global__ __launch_bounds__(256, 3) void gemm_out(
    const short* __restrict__ Ab, const short* __restrict__ Wob,
    const float* __restrict__ bo, float* __restrict__ out) {
  __shared__ short Ash[3][4096];
  __shared__ short Bsh[3][4096];
  const int tid = threadIdx.x;
  const int wid = tid >> 6, lane = tid & 63;
  const int g = lane >> 4, c = lane & 15;
  const int wm = wid >> 1, wn = wid & 1;
  const int bid = blockIdx.y * 8 + blockIdx.x;
  const int swz = (bid & 7) * 64 + (bid >> 3);
  const int m0 = (swz >> 3) * 128, n0 = (swz & 7) * 128;

  f32x4 acc[4][4];
#pragma unroll
  for (int i = 0; i < 4; i++)
#pragma unroll
    for (int j = 0; j < 4; j++) acc[i][j] = (f32x4){0.f, 0.f, 0.f, 0.f};

  const int srow = lane >> 2;
  const int scol = ((lane & 3) ^ ((lane >> 3) & 3)) * 8;
  const short* AgL = Ab + (long)(m0 + wid * 32 + srow) * 1024 + scol;
  const short* BgL = Wob + (long)(n0 + wid * 32 + srow) * 1024 + scol;
  const int dst0 = (wid * 32) * 32;
  const int dst1 = (wid * 32 + 16) * 32;
  const int ck = g ^ ((c >> 1) & 3);

#define OUT_STG(bs, ko) do { \
    GLD_LDS16(AgL + (ko), &Ash[bs][dst0]); \
    GLD_LDS16(AgL + (ko) + 16 * 1024, &Ash[bs][dst1]); \
    GLD_LDS16(BgL + (ko), &Bsh[bs][dst0]); \
    GLD_LDS16(BgL + (ko) + 16 * 1024, &Bsh[bs][dst1]); \
  } while (0)

  OUT_STG(0, 0);
  OUT_STG(1, 32);
  asm volatile("s_waitcnt vmcnt(4)" ::: "memory");
  __builtin_amdgcn_s_barrier();

  bf16x8 af[2][4], bfr[2][4];
#pragma unroll
  for (int i = 0; i < 4; i++)
    af[0][i] = *(const bf16x8*)&Ash[0][(wm * 64 + i * 16 + c) * 32 + ck * 8];
#pragma unroll
  for (int j = 0; j < 4; j++)
    bfr[0][j] = *(const bf16x8*)&Bsh[0][(wn * 64 + j * 16 + c) * 32 + ck * 8];

#pragma unroll
  for (int kt = 0; kt < 32; ++kt) {
    const int cur = kt & 1, nxt = cur ^ 1;
    __builtin_amdgcn_s_setprio(1);
#pragma unroll
    for (int i = 0; i < 2; i++)
#pragma unroll
      for (int j = 0; j < 4; j++)
        acc[i][j] = __builtin_amdgcn_mfma_f32_16x16x32_bf16(af[cur][i], bfr[cur][j], acc[i][j], 0, 0, 0);
    __builtin_amdgcn_s_setprio(0);
    __builtin_amdgcn_sched_barrier(0);
    if (kt < 31) {
      asm volatile("s_waitcnt vmcnt(0)" ::: "memory");
      __builtin_amdgcn_s_barrier();
      if (kt < 30) OUT_STG((kt + 2) % 3, (kt + 2) * 32);
      const int bn = (kt + 1) % 3;
#pragma unroll
      for (int i = 0; i < 4; i++)
        af[nxt][i] = *(const bf16x8*)&Ash[bn][(wm * 64 + i * 16 + c) * 32 + ck * 8];
#pragma unroll
      for (int j = 0; j < 4; j++)
        bfr[nxt][j] = *(const bf16x8*)&Bsh[bn][(wn * 64 + j * 16 + c) * 32 + ck * 8];
      __builtin_amdgcn_sched_barrier(0);
    }
    __builtin_amdgcn_s_setprio(1);
#pragma unroll
    for (int i = 2; i < 4; i++)
#pragma unroll
      for (int j = 0; j < 4; j++)
        acc[i][j] = __builtin_amdgcn_mfma_f32_16x16x32_bf16(af[cur][i], bfr[cur][j], acc[i][j], 0, 0, 0);
    __builtin_amdgcn_s_setprio(0);
  }
#undef OUT_STG

  for (int jt = 0; jt < 4; jt++) {
    const int j = n0 + wn * 64 + jt * 16 + c;
    const float bias = bo[j];
    for (int i = 0; i < 4; i++) {
      const int rbase = m0 + wm * 64 + i * 16 + g * 4;
      for (int reg = 0; reg < 4; reg++)
        out[(long)(rbase + reg) * 1024 + j] = acc[i][jt][reg] + bias;
    }
  }
}

// ---------------- launcher ----------------
extern "C" void kernel_launch(void* const* d_in, const int* in_sizes, int n_in,
                              void* d_out, int out_size, void* d_ws, size_t ws_size,
                              hipStream_t stream) {
  const float* hs = (const float*)d_in[0];
  const float* rpe = (const float*)d_in[1];
  const int* amask = (const int*)d_in[2];
  const float* Wqkv = (const float*)d_in[3];
  const float* bqkv = (const float*)d_in[4];
  const float* Wo = (const float*)d_in[5];
  const float* bo = (const float*)d_in[6];
  float* out = (float*)d_out;

  char* ws = (char*)d_ws;
  auto alloc = [&](size_t bytes) {
    char* p = ws;
    ws += (bytes + 255) & ~(size_t)255;
    return p;
  };
  short* Xb = (short*)alloc(8192LL * 1024 * 2);
  short* Wqkvb = (short*)alloc(3072LL * 1024 * 2);
  short* Wob = (short*)alloc(1024LL * 1024 * 2);
  float* cosT = (float*)alloc(1024 * 32 * 4);
  float* sinT = (float*)alloc(1024 * 32 * 4);
  unsigned char* maskt = (unsigned char*)alloc(8LL * 1024 * 1024);  // byte mask table
  short* qb = (short*)alloc(128LL * 1024 * 64 * 2);
  short* kbuf = (short*)alloc(128LL * 1024 * 64 * 2);
  short* vbuf = (short*)alloc(128LL * 1024 * 64 * 2);
  short* vTb = (short*)alloc(128LL * 1024 * 64 * 2);
  short* attno = (short*)alloc(8192LL * 1024 * 2);

  prep_all<<<20608, 256, 0, stream>>>(amask, maskt, hs, Wqkv, Wo, Xb, Wqkvb, Wob,
                                      rpe, cosT, sinT);
  gemm_qkv<<<dim3(12, 64), 256, 0, stream>>>(Xb, Wqkvb, bqkv, cosT, sinT, qb, kbuf, vbuf);
  transpose_v<<<dim3(16, 128), 256, 0, stream>>>(vbuf, vTb);
  flash_attn<<<dim3(8, 128), 512, 0, stream>>>(qb, kbuf, vTb, maskt, attno);
  gemm_out<<<dim3(8, 64), 256, 0, stream>>>(attno, Wob, bo, out);
}

// Round 15
// 272.924 us; speedup vs baseline: 1.0606x; 1.0453x over previous
//
#include <hip/hip_runtime.h>
#include <hip/hip_bf16.h>

typedef short bf16x8 __attribute__((ext_vector_type(8)));
typedef short bf16x4 __attribute__((ext_vector_type(4)));
typedef float f32x4 __attribute__((ext_vector_type(4)));
typedef unsigned int u32;
typedef unsigned long long u64;

#define GLD_LDS16(gp, lp) \
  __builtin_amdgcn_global_load_lds((const __attribute__((address_space(1))) u32*)(gp), \
                                   (__attribute__((address_space(3))) u32*)(lp), 16, 0, 0)

__device__ __forceinline__ short f2bf(float f) {
  u32 u = __builtin_bit_cast(u32, f);
  u = (u + 0x7fffu + ((u >> 16) & 1u)) >> 16;
  return (short)u;
}

// gfx950 has no cvt_pk_bf16 builtin (m240) -- hardware op via inline asm.
__device__ __forceinline__ u32 pack2_bf16(float a, float b) {
#if __has_builtin(__builtin_amdgcn_cvt_pk_bf16_f32)
  typedef __bf16 bf16v2 __attribute__((ext_vector_type(2)));
  bf16v2 r = __builtin_amdgcn_cvt_pk_bf16_f32(a, b);
  return __builtin_bit_cast(u32, r);
#else
  u32 r;
  asm("v_cvt_pk_bf16_f32 %0, %1, %2" : "=v"(r) : "v"(a), "v"(b));
  return r;
#endif
}

__device__ __forceinline__ float exp2_fast(float x) {
#if __has_builtin(__builtin_amdgcn_exp2f)
  return __builtin_amdgcn_exp2f(x);
#else
  return exp2f(x);
#endif
}

// duplicate two mask bytes of src into bf16 halves: sel [b,b,b',b'] -> 0xFFFF/0 pairs
__device__ __forceinline__ u32 bytemask2(u32 src, u32 sel) {
  u32 r;
  asm("v_perm_b32 %0, %1, %1, %2" : "=v"(r) : "v"(src), "v"(sel));
  return r;
}

// ---------------- fused prep: mask byte-table (8192) + cvt (12288) + rope (128) ----
__global__ __launch_bounds__(256) void prep_all(
    const int* __restrict__ m, unsigned char* __restrict__ maskt,
    const float* __restrict__ hs, const float* __restrict__ wqkv,
    const float* __restrict__ wo, short* __restrict__ xb,
    short* __restrict__ wqkvb, short* __restrict__ wob,
    const float* __restrict__ rpe, float* __restrict__ cosT,
    float* __restrict__ sinT) {
  int b = blockIdx.x;
  if (b < 8192) {
    // t[b][q][k] = m[b][q][k] ? 0xFF : 0  (8 MB, L3-resident)
    int i = b * 1024 + threadIdx.x * 4;
    int4 v = *(const int4*)(m + i);
    uchar4 o;
    o.x = v.x ? 0xFFu : 0u;
    o.y = v.y ? 0xFFu : 0u;
    o.z = v.z ? 0xFFu : 0u;
    o.w = v.w ? 0xFFu : 0u;
    *(uchar4*)(maskt + i) = o;
    return;
  }
  b -= 8192;
  if (b < 12288) {
    const float* in;
    short* out;
    int base;
    if (b < 8192) {
      in = hs; out = xb; base = b * 1024;
    } else if (b < 8192 + 3072) {
      in = wqkv; out = wqkvb; base = (b - 8192) * 1024;
    } else {
      in = wo; out = wob; base = (b - 11264) * 1024;
    }
    int i = base + threadIdx.x * 4;
    float4 v = *(const float4*)(in + i);
    short4 o;
    o.x = f2bf(v.x); o.y = f2bf(v.y); o.z = f2bf(v.z); o.w = f2bf(v.w);
    *(short4*)(out + i) = o;
    return;
  }
  b -= 12288;
  int i = b * 256 + threadIdx.x;  // 32768 = 1024*32
  float v = rpe[i];
  cosT[i] = cosf(v);
  sinT[i] = sinf(v);
}

// ---------------- GEMM 1 v7 (round-10 best: 70us; plateau of the 2-phase family) ----
// Tile 128x256, BK=64, 512 thr = 8 waves (2M x 4N), 3-buffer LDS rotation.
// Per K-tile: {vmcnt(6); s_barrier; STG(kt+2); ds_read; 32 MFMA}.
// Structural note: v8b (2blk/CU), v9 (128^2), v10 (64x128/wave) all land 70-88us;
// ~70us = 735 TF is this schedule family's ceiling at this shape.
__global__ __launch_bounds__(512, 2) void gemm_qkv(
    const short* __restrict__ Xb, const short* __restrict__ Wb,
    const float* __restrict__ bqkv, const float* __restrict__ cosT,
    const float* __restrict__ sinT, short* __restrict__ qb,
    short* __restrict__ kbuf, short* __restrict__ vbuf) {
  __shared__ short lds[3][24576];  // [buf][A:128x64 | B:256x64]
  const int tid = threadIdx.x;
  const int wid = tid >> 6, lane = tid & 63;
  const int g = lane >> 4, c = lane & 15;
  const int wm = wid >> 2, wn = wid & 3;
  const int bid = blockIdx.y * 12 + blockIdx.x;
  const int swz = (bid & 7) * 96 + (bid >> 3);
  const int m0 = (swz / 12) * 128, n0 = (swz % 12) * 256;

  f32x4 acc[4][4];
#pragma unroll
  for (int i = 0; i < 4; i++)
#pragma unroll
    for (int j = 0; j < 4; j++) acc[i][j] = (f32x4){0.f, 0.f, 0.f, 0.f};

  const int trow = tid >> 3;
  const int gch = ((tid & 7) ^ (trow & 7)) * 8;
  const short* Ag = Xb + (long)(m0 + trow) * 1024 + gch;
  const short* Bg = Wb + (long)(n0 + trow) * 1024 + gch;
  const int lo = tid * 8;

  const int fA = (wm * 64 + c) * 64;
  const int fB = 8192 + (wn * 64 + c) * 64;
  const int ck0 = (g ^ (c & 7)) * 8;

#define QKV_STG(bs, ko) do { \
    GLD_LDS16(Ag + (ko),              &lds[bs][lo]); \
    GLD_LDS16(Ag + (ko) + 64 * 1024,  &lds[bs][4096 + lo]); \
    GLD_LDS16(Bg + (ko),              &lds[bs][8192 + lo]); \
    GLD_LDS16(Bg + (ko) + 64 * 1024,  &lds[bs][12288 + lo]); \
    GLD_LDS16(Bg + (ko) + 128 * 1024, &lds[bs][16384 + lo]); \
    GLD_LDS16(Bg + (ko) + 192 * 1024, &lds[bs][20480 + lo]); \
  } while (0)

  QKV_STG(0, 0);
  QKV_STG(1, 64);

#pragma unroll
  for (int kt = 0; kt < 16; ++kt) {
    if (kt < 15) {
      asm volatile("s_waitcnt vmcnt(6)" ::: "memory");
    } else {
      asm volatile("s_waitcnt vmcnt(0)" ::: "memory");
    }
    __builtin_amdgcn_s_barrier();
    __builtin_amdgcn_sched_barrier(0);
    if (kt < 14) QKV_STG((kt + 2) % 3, (kt + 2) * 64);
    const short* Bf = &lds[kt % 3][0];
    bf16x8 fa0[4], fb0[4], fa1[4], fb1[4];
#pragma unroll
    for (int mf = 0; mf < 4; mf++) fa0[mf] = *(const bf16x8*)&Bf[fA + mf * 1024 + ck0];
#pragma unroll
    for (int nf = 0; nf < 4; nf++) fb0[nf] = *(const bf16x8*)&Bf[fB + nf * 1024 + ck0];
#pragma unroll
    for (int mf = 0; mf < 4; mf++) fa1[mf] = *(const bf16x8*)&Bf[fA + mf * 1024 + (ck0 ^ 32)];
#pragma unroll
    for (int nf = 0; nf < 4; nf++) fb1[nf] = *(const bf16x8*)&Bf[fB + nf * 1024 + (ck0 ^ 32)];
    __builtin_amdgcn_s_setprio(1);
#pragma unroll
    for (int mf = 0; mf < 4; mf++)
#pragma unroll
      for (int nf = 0; nf < 4; nf++)
        acc[mf][nf] = __builtin_amdgcn_mfma_f32_16x16x32_bf16(fb0[nf], fa0[mf], acc[mf][nf], 0, 0, 0);
#pragma unroll
    for (int mf = 0; mf < 4; mf++)
#pragma unroll
      for (int nf = 0; nf < 4; nf++)
        acc[mf][nf] = __builtin_amdgcn_mfma_f32_16x16x32_bf16(fb1[nf], fa1[mf], acc[mf][nf], 0, 0, 0);
    __builtin_amdgcn_s_setprio(0);
  }
#undef QKV_STG

  for (int jt = 0; jt < 4; jt++) {
    const int chan = n0 + wn * 64 + jt * 16 + g * 4;
    const int three = chan >> 10;
    const int hh = (chan >> 6) & 15;
    const int d = chan & 63;
    const float4 bq = *(const float4*)&bqkv[chan];
    for (int i = 0; i < 4; i++) {
      const int r = m0 + wm * 64 + i * 16 + c;
      const int l = r >> 3, b = r & 7;
      float v0 = acc[i][jt][0] + bq.x;
      float v1 = acc[i][jt][1] + bq.y;
      float v2 = acc[i][jt][2] + bq.z;
      float v3 = acc[i][jt][3] + bq.w;
      const long doff = ((long)(b * 16 + hh) * 1024 + l) * 64 + d;
      if (three == 2) {
        uint2 o = {pack2_bf16(v0, v1), pack2_bf16(v2, v3)};
        *(uint2*)&vbuf[doff] = o;
      } else {
        const float4 cs = *(const float4*)&cosT[l * 32 + (d & 31)];
        const float4 sn = *(const float4*)&sinT[l * 32 + (d & 31)];
        float e0 = v0 * cs.x - v1 * sn.x;
        float o0 = v1 * cs.y + v0 * sn.y;
        float e1 = v2 * cs.z - v3 * sn.z;
        float o1 = v3 * cs.w + v2 * sn.w;
        short* dst;
        if (three == 0) {
          const float S = 0.18033688011f;  // 1/sqrt(D) * log2(e)
          e0 *= S; o0 *= S; e1 *= S; o1 *= S;
          dst = qb;
        } else {
          dst = kbuf;
        }
        uint2 o = {pack2_bf16(e0, o0), pack2_bf16(e1, o1)};
        *(uint2*)&dst[doff] = o;
      }
    }
  }
}

// ---------------- V transpose: (B,H,L,D) -> (B,H,D,L) ----------------
__global__ __launch_bounds__(256) void transpose_v(const short* __restrict__ vbuf,
                                                   short* __restrict__ vTb) {
  __shared__ short T[64 * 72];
  const int bh = blockIdx.y;
  const int l0 = blockIdx.x * 64;
  const int t = threadIdx.x;
  const int row = t >> 3;
  const int cc = (t & 7) * 8;
  const short* src = vbuf + ((long)bh * 1024 + l0) * 64;
  for (int p = 0; p < 2; p++) {
    int lr = row + p * 32;
    *(bf16x8*)&T[lr * 72 + cc] = *(const bf16x8*)&src[(long)lr * 64 + cc];
  }
  __syncthreads();
  short* dst = vTb + (long)bh * 64 * 1024 + l0;
  for (int p = 0; p < 2; p++) {
    int d = row + p * 32;
    bf16x8 v;
    for (int j = 0; j < 8; j++) v[j] = T[(cc + j) * 72 + d];
    *(bf16x8*)&dst[(long)d * 1024 + cc] = v;
  }
}

// ---------------- flash attention v10b: 512 thr / 8 waves / 128 q-rows ----------------
// (512, 4): 128-VGPR cap, no spill; LDS 32KB -> 4 blocks/CU = 32 waves/CU.
__global__ __launch_bounds__(512, 4) void flash_attn(
    const short* __restrict__ qb, const short* __restrict__ kbuf,
    const short* __restrict__ vTb, const unsigned char* __restrict__ maskt,
    short* __restrict__ attno) {
  __shared__ short K0[64 * 64], K1[64 * 64];
  __shared__ short V0[64 * 64], V1[64 * 64];
  const int t = threadIdx.x;
  const int wid = t >> 6, lane = t & 63;
  const int g = lane >> 4, c = lane & 15;
  const int bid = blockIdx.y * 8 + blockIdx.x;
  const int swz = (bid & 7) * 128 + (bid >> 3);
  const int q0 = (swz & 7) * 128;
  const int bh = swz >> 3;
  const int b = bh >> 4;
  const int h = bh & 15;
  const long qoff = (long)bh * 1024 * 64;
  const int qrow = q0 + wid * 16 + c;  // wid 0-7 -> 128 q-rows per block

  const u32 SEL01 = 0x01010000u;  // dst bytes = [b0,b0,b1,b1]
  const u32 SEL23 = 0x03030202u;  // dst bytes = [b2,b2,b3,b3]

  bf16x8 aq0, aq1;
  {
    const short* qp = qb + qoff + (long)qrow * 64;
    aq0 = *(const bf16x8*)(qp + g * 8);
    aq1 = *(const bf16x8*)(qp + 32 + g * 8);
  }

  f32x4 Od[4];
  for (int i = 0; i < 4; i++) Od[i] = (f32x4){0.f, 0.f, 0.f, 0.f};
  f32x4 Ld = (f32x4){0.f, 0.f, 0.f, 0.f};
  float m_run = -1e30f;

  bf16x8 avOnes8;
  {
    union { bf16x8 v; u32 u[4]; } av;
    u32 o1 = (c == 0) ? 0x3F803F80u : 0u;
    av.u[0] = av.u[1] = av.u[2] = av.u[3] = o1;
    avOnes8 = av.v;
  }

  const unsigned char* mrow8 = maskt + ((long)b * 1024 + qrow) * 1024 + g * 8;
  const short* Kg = kbuf + qoff;
  const short* Vg = vTb + qoff;

  const int rr = t >> 3;
  const int sch = (((t & 7) ^ (rr & 7)) & 7) * 8;
  const int kp = (rr & 32) | (((rr & 15) >> 2) << 3) | (((rr >> 4) & 1) << 2) | (rr & 3);
  const int ldsb = (wid * 8) * 64;  // wave-uniform dest base (shorts)

  const int ck0 = g ^ (c & 7);
  const int kOff0 = c * 64 + ck0 * 8;
  const int kOff1 = c * 64 + (ck0 ^ 4) * 8;
  int vOff32[2];
  for (int kg = 0; kg < 2; kg++)
    vOff32[kg] = c * 64 + (((kg * 4 + g) ^ (c & 7)) * 8);

#define STAGE(KD, VD, ktn) do { \
    GLD_LDS16(Kg + (long)((ktn) + kp) * 64 + sch, &KD[ldsb]); \
    GLD_LDS16(Vg + (long)rr * 1024 + (ktn) + sch, &VD[ldsb]); \
  } while (0)

#define TILE(KB, VB, KP, VP, ki) do { \
    __syncthreads(); /* drains prefetch issued a full tile of compute ago */ \
    STAGE(KP, VP, (((ki) + 1) & 15) * 64); \
    const uint2 w0 = *(const uint2*)&mrow8[(ki) * 64]; \
    const uint2 w1 = *(const uint2*)&mrow8[(ki) * 64 + 32]; \
    f32x4 z[4]; \
    __builtin_amdgcn_s_setprio(1); \
    for (int nt = 0; nt < 4; nt++) { \
      bf16x8 bk0 = *(const bf16x8*)&KB[kOff0 + nt * 1024]; \
      bf16x8 bk1 = *(const bf16x8*)&KB[kOff1 + nt * 1024]; \
      f32x4 zz = (f32x4){0.f, 0.f, 0.f, 0.f}; \
      zz = __builtin_amdgcn_mfma_f32_16x16x32_bf16(bk0, aq0, zz, 0, 0, 0); \
      zz = __builtin_amdgcn_mfma_f32_16x16x32_bf16(bk1, aq1, zz, 0, 0, 0); \
      z[nt] = zz; \
    } \
    __builtin_amdgcn_s_setprio(0); \
    float mx = fmaxf(fmaxf(fmaxf(z[0][0], z[0][1]), fmaxf(z[0][2], z[0][3])), \
                     fmaxf(fmaxf(z[1][0], z[1][1]), fmaxf(z[1][2], z[1][3]))); \
    mx = fmaxf(mx, fmaxf(fmaxf(fmaxf(z[2][0], z[2][1]), fmaxf(z[2][2], z[2][3])), \
                         fmaxf(fmaxf(z[3][0], z[3][1]), fmaxf(z[3][2], z[3][3])))); \
    if (__ballot(mx > m_run + 8.f)) { /* rare after warm-up (T13) */ \
      mx = fmaxf(mx, __shfl_xor(mx, 16, 64)); \
      mx = fmaxf(mx, __shfl_xor(mx, 32, 64)); \
      float mnew = fmaxf(m_run, mx); \
      float al = exp2_fast(m_run - mnew); \
      for (int dt = 0; dt < 4; dt++) { \
        Od[dt][0] *= al; Od[dt][1] *= al; Od[dt][2] *= al; Od[dt][3] *= al; \
      } \
      Ld[0] *= al; \
      m_run = mnew; \
    } \
    union { bf16x8 v; u32 u[4]; } puA, puB; \
    { \
      float p0 = exp2_fast(z[0][0] - m_run), p1 = exp2_fast(z[0][1] - m_run); \
      float p2 = exp2_fast(z[0][2] - m_run), p3 = exp2_fast(z[0][3] - m_run); \
      float p4 = exp2_fast(z[1][0] - m_run), p5 = exp2_fast(z[1][1] - m_run); \
      float p6 = exp2_fast(z[1][2] - m_run), p7 = exp2_fast(z[1][3] - m_run); \
      puA.u[0] = pack2_bf16(p0, p1) & bytemask2(w0.x, SEL01); \
      puA.u[1] = pack2_bf16(p2, p3) & bytemask2(w0.x, SEL23); \
      puA.u[2] = pack2_bf16(p4, p5) & bytemask2(w0.y, SEL01); \
      puA.u[3] = pack2_bf16(p6, p7) & bytemask2(w0.y, SEL23); \
    } \
    { \
      float p0 = exp2_fast(z[2][0] - m_run), p1 = exp2_fast(z[2][1] - m_run); \
      float p2 = exp2_fast(z[2][2] - m_run), p3 = exp2_fast(z[2][3] - m_run); \
      float p4 = exp2_fast(z[3][0] - m_run), p5 = exp2_fast(z[3][1] - m_run); \
      float p6 = exp2_fast(z[3][2] - m_run), p7 = exp2_fast(z[3][3] - m_run); \
      puB.u[0] = pack2_bf16(p0, p1) & bytemask2(w1.x, SEL01); \
      puB.u[1] = pack2_bf16(p2, p3) & bytemask2(w1.x, SEL23); \
      puB.u[2] = pack2_bf16(p4, p5) & bytemask2(w1.y, SEL01); \
      puB.u[3] = pack2_bf16(p6, p7) & bytemask2(w1.y, SEL23); \
    } \
    __builtin_amdgcn_s_setprio(1); \
    Ld = __builtin_amdgcn_mfma_f32_16x16x32_bf16(avOnes8, puA.v, Ld, 0, 0, 0); \
    for (int dt = 0; dt < 4; dt++) { \
      bf16x8 av = *(const bf16x8*)&VB[vOff32[0] + dt * 1024]; \
      Od[dt] = __builtin_amdgcn_mfma_f32_16x16x32_bf16(av, puA.v, Od[dt], 0, 0, 0); \
    } \
    Ld = __builtin_amdgcn_mfma_f32_16x16x32_bf16(avOnes8, puB.v, Ld, 0, 0, 0); \
    for (int dt = 0; dt < 4; dt++) { \
      bf16x8 av = *(const bf16x8*)&VB[vOff32[1] + dt * 1024]; \
      Od[dt] = __builtin_amdgcn_mfma_f32_16x16x32_bf16(av, puB.v, Od[dt], 0, 0, 0); \
    } \
    __builtin_amdgcn_s_setprio(0); \
  } while (0)

  STAGE(K0, V0, 0);
  for (int ki = 0; ki < 16; ki += 2) {
    TILE(K0, V0, K1, V1, ki);
    TILE(K1, V1, K0, V0, ki + 1);
  }
#undef TILE
#undef STAGE

  float lsum = __shfl(Ld[0], c, 64);
  float inv = 1.f / lsum;
  long rbase = ((long)qrow * 8 + b) * 1024 + h * 64 + g * 4;
  for (int dt = 0; dt < 4; dt++) {
    union { bf16x4 v; u32 u[2]; } o;
    o.u[0] = pack2_bf16(Od[dt][0] * inv, Od[dt][1] * inv);
    o.u[1] = pack2_bf16(Od[dt][2] * inv, Od[dt][3] * inv);
    *(bf16x4*)&attno[rbase + dt * 16] = o.v;
  }
}

// ---------------- GEMM 2 v4 (proven in 280/282/286 builds) ----------------
__global__ __launch_bounds__(256, 3) void gemm_out(
    const short* __restrict__ Ab, const short* __restrict__ Wob,
    const float* __restrict__ bo, float* __restrict__ out) {
  __shared__ short Ash[3][4096];
  __shared__ short Bsh[3][4096];
  const int tid = threadIdx.x;
  const int wid = tid >> 6, lane = tid & 63;
  const int g = lane >> 4, c = lane & 15;
  const int wm = wid >> 1, wn = wid & 1;
  const int bid = blockIdx.y * 8 + blockIdx.x;
  const int swz = (bid & 7) * 64 + (bid >> 3);
  const int m0 = (swz >> 3) * 128, n0 = (swz & 7) * 128;

  f32x4 acc[4][4];
#pragma unroll
  for (int i = 0; i < 4; i++)
#pragma unroll
    for (int j = 0; j < 4; j++) acc[i][j] = (f32x4){0.f, 0.f, 0.f, 0.f};

  const int srow = lane >> 2;
  const int scol = ((lane & 3) ^ ((lane >> 3) & 3)) * 8;
  const short* AgL = Ab + (long)(m0 + wid * 32 + srow) * 1024 + scol;
  const short* BgL = Wob + (long)(n0 + wid * 32 + srow) * 1024 + scol;
  const int dst0 = (wid * 32) * 32;
  const int dst1 = (wid * 32 + 16) * 32;
  const int ck = g ^ ((c >> 1) & 3);

#define OUT_STG(bs, ko) do { \
    GLD_LDS16(AgL + (ko), &Ash[bs][dst0]); \
    GLD_LDS16(AgL + (ko) + 16 * 1024, &Ash[bs][dst1]); \
    GLD_LDS16(BgL + (ko), &Bsh[bs][dst0]); \
    GLD_LDS16(BgL + (ko) + 16 * 1024, &Bsh[bs][dst1]); \
  } while (0)

  OUT_STG(0, 0);
  OUT_STG(1, 32);
  asm volatile("s_waitcnt vmcnt(4)" ::: "memory");
  __builtin_amdgcn_s_barrier();

  bf16x8 af[2][4], bfr[2][4];
#pragma unroll
  for (int i = 0; i < 4; i++)
    af[0][i] = *(const bf16x8*)&Ash[0][(wm * 64 + i * 16 + c) * 32 + ck * 8];
#pragma unroll
  for (int j = 0; j < 4; j++)
    bfr[0][j] = *(const bf16x8*)&Bsh[0][(wn * 64 + j * 16 + c) * 32 + ck * 8];

#pragma unroll
  for (int kt = 0; kt < 32; ++kt) {
    const int cur = kt & 1, nxt = cur ^ 1;
    __builtin_amdgcn_s_setprio(1);
#pragma unroll
    for (int i = 0; i < 2; i++)
#pragma unroll
      for (int j = 0; j < 4; j++)
        acc[i][j] = __builtin_amdgcn_mfma_f32_16x16x32_bf16(af[cur][i], bfr[cur][j], acc[i][j], 0, 0, 0);
    __builtin_amdgcn_s_setprio(0);
    __builtin_amdgcn_sched_barrier(0);
    if (kt < 31) {
      asm volatile("s_waitcnt vmcnt(0)" ::: "memory");
      __builtin_amdgcn_s_barrier();
      if (kt < 30) OUT_STG((kt + 2) % 3, (kt + 2) * 32);
      const int bn = (kt + 1) % 3;
#pragma unroll
      for (int i = 0; i < 4; i++)
        af[nxt][i] = *(const bf16x8*)&Ash[bn][(wm * 64 + i * 16 + c) * 32 + ck * 8];
#pragma unroll
      for (int j = 0; j < 4; j++)
        bfr[nxt][j] = *(const bf16x8*)&Bsh[bn][(wn * 64 + j * 16 + c) * 32 + ck * 8];
      __builtin_amdgcn_sched_barrier(0);
    }
    __builtin_amdgcn_s_setprio(1);
#pragma unroll
    for (int i = 2; i < 4; i++)
#pragma unroll
      for (int j = 0; j < 4; j++)
        acc[i][j] = __builtin_amdgcn_mfma_f32_16x16x32_bf16(af[cur][i], bfr[cur][j], acc[i][j], 0, 0, 0);
    __builtin_amdgcn_s_setprio(0);
  }
#undef OUT_STG

  for (int jt = 0; jt < 4; jt++) {
    const int j = n0 + wn * 64 + jt * 16 + c;
    const float bias = bo[j];
    for (int i = 0; i < 4; i++) {
      const int rbase = m0 + wm * 64 + i * 16 + g * 4;
      for (int reg = 0; reg < 4; reg++)
        out[(long)(rbase + reg) * 1024 + j] = acc[i][jt][reg] + bias;
    }
  }
}

// ---------------- launcher ----------------
extern "C" void kernel_launch(void* const* d_in, const int* in_sizes, int n_in,
                              void* d_out, int out_size, void* d_ws, size_t ws_size,
                              hipStream_t stream) {
  const float* hs = (const float*)d_in[0];
  const float* rpe = (const float*)d_in[1];
  const int* amask = (const int*)d_in[2];
  const float* Wqkv = (const float*)d_in[3];
  const float* bqkv = (const float*)d_in[4];
  const float* Wo = (const float*)d_in[5];
  const float* bo = (const float*)d_in[6];
  float* out = (float*)d_out;

  char* ws = (char*)d_ws;
  auto alloc = [&](size_t bytes) {
    char* p = ws;
    ws += (bytes + 255) & ~(size_t)255;
    return p;
  };
  short* Xb = (short*)alloc(8192LL * 1024 * 2);
  short* Wqkvb = (short*)alloc(3072LL * 1024 * 2);
  short* Wob = (short*)alloc(1024LL * 1024 * 2);
  float* cosT = (float*)alloc(1024 * 32 * 4);
  float* sinT = (float*)alloc(1024 * 32 * 4);
  unsigned char* maskt = (unsigned char*)alloc(8LL * 1024 * 1024);  // byte mask table
  short* qb = (short*)alloc(128LL * 1024 * 64 * 2);
  short* kbuf = (short*)alloc(128LL * 1024 * 64 * 2);
  short* vbuf = (short*)alloc(128LL * 1024 * 64 * 2);
  short* vTb = (short*)alloc(128LL * 1024 * 64 * 2);
  short* attno = (short*)alloc(8192LL * 1024 * 2);

  prep_all<<<20608, 256, 0, stream>>>(amask, maskt, hs, Wqkv, Wo, Xb, Wqkvb, Wob,
                                      rpe, cosT, sinT);
  gemm_qkv<<<dim3(12, 64), 512, 0, stream>>>(Xb, Wqkvb, bqkv, cosT, sinT, qb, kbuf, vbuf);
  transpose_v<<<dim3(16, 128), 256, 0, stream>>>(vbuf, vTb);
  flash_attn<<<dim3(8, 128), 512, 0, stream>>>(qb, kbuf, vTb, maskt, attno);
  gemm_out<<<dim3(8, 64), 256, 0, stream>>>(attno, Wob, bo, out);
}